// Round 1
// baseline (127.290 us; speedup 1.0000x reference)
//
#include <hip/hip_runtime.h>
#include <math.h>

#define NB 1024
#define N 256
#define ROWS 8
#define EPS 1e-6f
#define SQRT_EPS 1e-3f   // sqrt(1e-6)

__device__ __forceinline__ float sigmoidf(float x) {
    return 1.0f / (1.0f + __expf(-x));
}

// block-wide (256-thread) sum; red must be __shared__ float[4]
__device__ __forceinline__ float block_sum(float val, float* red, int tid) {
    #pragma unroll
    for (int off = 32; off > 0; off >>= 1)
        val += __shfl_down(val, off, 64);
    __syncthreads();               // protect red from previous use
    if ((tid & 63) == 0) red[tid >> 6] = val;
    __syncthreads();
    return red[0] + red[1] + red[2] + red[3];
}

__global__ __launch_bounds__(256) void mlp_kernel(
    const float* __restrict__ x,
    const float* __restrict__ Wd1, const float* __restrict__ bd1,
    const float* __restrict__ Wd2, const float* __restrict__ bd2,
    const float* __restrict__ Wu1, const float* __restrict__ bu1,
    const float* __restrict__ Wu2, const float* __restrict__ bu2,
    const float* __restrict__ Wm1, const float* __restrict__ bm1,
    const float* __restrict__ Wm2, const float* __restrict__ bm2,
    const float* __restrict__ v,
    float* __restrict__ out_mean, float* __restrict__ out_z,
    float* __restrict__ ws_a, float* __restrict__ ws_tp, float* __restrict__ ws_s)
{
    __shared__ float xs[ROWS][N];
    __shared__ float hd[ROWS][N];
    __shared__ float hu[ROWS][N];
    __shared__ float hm[ROWS][N];
    __shared__ float red[4];

    const int tid = threadIdx.x;
    const int b0  = blockIdx.x * ROWS;

    // ---- load x rows (coalesced float4) ----
    {
        const float4* xg  = (const float4*)(x + (size_t)b0 * N);
        float4*       xsv = (float4*)&xs[0][0];
        #pragma unroll
        for (int i = 0; i < (ROWS * N / 4) / 256; ++i)
            xsv[tid + i * 256] = xg[tid + i * 256];
    }
    __syncthreads();

    // ---- layer 1 of all three MLPs (thread t = output neuron t) ----
    {
        float accd[ROWS], accu[ROWS], accm[ROWS];
        #pragma unroll
        for (int r = 0; r < ROWS; ++r) { accd[r] = 0.f; accu[r] = 0.f; accm[r] = 0.f; }
        const float4* wd = (const float4*)(Wd1 + (size_t)tid * N);
        const float4* wu = (const float4*)(Wu1 + (size_t)tid * N);
        const float4* wm = (const float4*)(Wm1 + (size_t)tid * N);
        for (int k4 = 0; k4 < N / 4; ++k4) {
            float4 w1 = wd[k4];
            float4 w2 = wu[k4];
            float4 w3 = wm[k4];
            #pragma unroll
            for (int r = 0; r < ROWS; ++r) {
                float4 xv = ((const float4*)xs[r])[k4];
                accd[r] += w1.x * xv.x + w1.y * xv.y + w1.z * xv.z + w1.w * xv.w;
                accu[r] += w2.x * xv.x + w2.y * xv.y + w2.z * xv.z + w2.w * xv.w;
                accm[r] += w3.x * xv.x + w3.y * xv.y + w3.z * xv.z + w3.w * xv.w;
            }
        }
        float b1 = bd1[tid], b2 = bu1[tid], b3 = bm1[tid];
        #pragma unroll
        for (int r = 0; r < ROWS; ++r) {
            hd[r][tid] = sigmoidf(accd[r] + b1);
            hu[r][tid] = sigmoidf(accu[r] + b2);
            hm[r][tid] = tanhf(accm[r] + b3);
        }
    }
    __syncthreads();

    // ---- layer 2 of all three MLPs ----
    float d_[ROWS], u_[ROWS], m_[ROWS];
    {
        float accd[ROWS], accu[ROWS], accm[ROWS];
        #pragma unroll
        for (int r = 0; r < ROWS; ++r) { accd[r] = 0.f; accu[r] = 0.f; accm[r] = 0.f; }
        const float4* wd = (const float4*)(Wd2 + (size_t)tid * N);
        const float4* wu = (const float4*)(Wu2 + (size_t)tid * N);
        const float4* wm = (const float4*)(Wm2 + (size_t)tid * N);
        for (int k4 = 0; k4 < N / 4; ++k4) {
            float4 w1 = wd[k4];
            float4 w2 = wu[k4];
            float4 w3 = wm[k4];
            #pragma unroll
            for (int r = 0; r < ROWS; ++r) {
                float4 hdv = ((const float4*)hd[r])[k4];
                float4 huv = ((const float4*)hu[r])[k4];
                float4 hmv = ((const float4*)hm[r])[k4];
                accd[r] += w1.x * hdv.x + w1.y * hdv.y + w1.z * hdv.z + w1.w * hdv.w;
                accu[r] += w2.x * huv.x + w2.y * huv.y + w2.z * huv.z + w2.w * huv.w;
                accm[r] += w3.x * hmv.x + w3.y * hmv.y + w3.z * hmv.z + w3.w * hmv.w;
            }
        }
        float b1 = bd2[tid], b2 = bu2[tid], b3 = bm2[tid];
        #pragma unroll
        for (int r = 0; r < ROWS; ++r) {
            d_[r] = sigmoidf(accd[r] + b1);
            u_[r] = sigmoidf(accu[r] + b2);
            m_[r] = tanhf(accm[r] + b3);
        }
    }

    // ---- per-row closed-form epilogue ----
    #pragma unroll
    for (int r = 0; r < ROWS; ++r) {
        const size_t row = (size_t)(b0 + r) * N + tid;
        float dv = d_[r], uv = u_[r];
        float inv_d = 1.0f / dv;

        float Su = block_sum(uv, red, tid);
        float q  = block_sum(uv * uv * inv_d, red, tid);
        float utDu = q + EPS * Su * Su;
        float sqeta = rsqrtf(1.0f + utDu);            // sqrt(eta)
        float right = (1.0f - sqeta) / utDu;

        float a  = sqrtf(inv_d + EPS);
        float s  = uv * a + SQRT_EPS * (Su - uv);
        float tp = right * (uv * inv_d + EPS * Su);

        float vv = v[row];
        float Sv = block_sum(vv, red, tid);
        float sv = block_sum(s * vv, red, tid);

        float z = SQRT_EPS * Sv + (a - SQRT_EPS) * vv - tp * sv + m_[r];

        out_mean[row] = m_[r];
        out_z[row]    = z;
        ws_a[row]     = a;
        ws_tp[row]    = tp;
        ws_s[row]     = s;
    }
}

// R[b,i,j] = SQRT_EPS + (i==j)*(a_i - SQRT_EPS) - tp_i * s_j
__global__ __launch_bounds__(256) void r_kernel(
    const float* __restrict__ ws_a, const float* __restrict__ ws_tp,
    const float* __restrict__ ws_s, float* __restrict__ R)
{
    __shared__ float s_lds[N];
    __shared__ float a_lds[64];
    __shared__ float tp_lds[64];

    const int tid   = threadIdx.x;
    const int b     = blockIdx.x >> 2;
    const int chunk = blockIdx.x & 3;
    const int ibase = chunk * 64;

    s_lds[tid] = ws_s[(size_t)b * N + tid];
    if (tid < 64) {
        a_lds[tid]  = ws_a[(size_t)b * N + ibase + tid];
        tp_lds[tid] = ws_tp[(size_t)b * N + ibase + tid];
    }
    __syncthreads();

    const int j4 = tid & 63;      // which float4 along j
    const int il = tid >> 6;      // row within group of 4
    const float4 sv = ((const float4*)s_lds)[j4];
    float4* Rb = (float4*)(R + (size_t)b * N * N);
    const int jb = j4 * 4;

    #pragma unroll
    for (int it = 0; it < 16; ++it) {
        const int i_loc = it * 4 + il;
        const int i     = ibase + i_loc;
        const float a   = a_lds[i_loc];
        const float tp  = tp_lds[i_loc];
        float4 o;
        o.x = SQRT_EPS - tp * sv.x;
        o.y = SQRT_EPS - tp * sv.y;
        o.z = SQRT_EPS - tp * sv.z;
        o.w = SQRT_EPS - tp * sv.w;
        if (i >= jb && i < jb + 4) {
            const float add = a - SQRT_EPS;
            if      (i == jb)     o.x += add;
            else if (i == jb + 1) o.y += add;
            else if (i == jb + 2) o.z += add;
            else                  o.w += add;
        }
        Rb[(size_t)i * 64 + j4] = o;
    }
}

extern "C" void kernel_launch(void* const* d_in, const int* in_sizes, int n_in,
                              void* d_out, int out_size, void* d_ws, size_t ws_size,
                              hipStream_t stream) {
    const float* x   = (const float*)d_in[0];
    const float* Wd1 = (const float*)d_in[1];
    const float* bd1 = (const float*)d_in[2];
    const float* Wd2 = (const float*)d_in[3];
    const float* bd2 = (const float*)d_in[4];
    const float* Wu1 = (const float*)d_in[5];
    const float* bu1 = (const float*)d_in[6];
    const float* Wu2 = (const float*)d_in[7];
    const float* bu2 = (const float*)d_in[8];
    const float* Wm1 = (const float*)d_in[9];
    const float* bm1 = (const float*)d_in[10];
    const float* Wm2 = (const float*)d_in[11];
    const float* bm2 = (const float*)d_in[12];
    const float* v   = (const float*)d_in[13];

    float* out      = (float*)d_out;
    float* out_mean = out;                                   // [1024,256]
    float* R        = out + (size_t)NB * N;                  // [1024,256,256]
    float* out_z    = R + (size_t)NB * N * N;                // [1024,256]

    float* wsf   = (float*)d_ws;
    float* ws_a  = wsf;                    // [1024,256]
    float* ws_tp = wsf + (size_t)NB * N;   // [1024,256]
    float* ws_s  = wsf + (size_t)2 * NB * N;

    mlp_kernel<<<NB / ROWS, 256, 0, stream>>>(
        x, Wd1, bd1, Wd2, bd2, Wu1, bu1, Wu2, bu2, Wm1, bm1, Wm2, bm2, v,
        out_mean, out_z, ws_a, ws_tp, ws_s);

    r_kernel<<<NB * 4, 256, 0, stream>>>(ws_a, ws_tp, ws_s, R);
}

// Round 3
// 119.960 us; speedup vs baseline: 1.0611x; 1.0611x over previous
//
#include <hip/hip_runtime.h>
#include <math.h>

#define NB 1024
#define N 256
#define ROWS 4
#define EPS 1e-6f
#define SQRT_EPS 1e-3f   // sqrt(1e-6)

typedef float nfloat4 __attribute__((ext_vector_type(4)));

__device__ __forceinline__ float fast_rcp(float x) {
    return __builtin_amdgcn_rcpf(x);      // v_rcp_f32, ~1 ulp
}

__device__ __forceinline__ float sigmoidf(float x) {
    return fast_rcp(1.0f + __expf(-x));
}

__device__ __forceinline__ float fast_tanh(float x) {
    float ax = fabsf(x);
    float e  = __expf(2.0f * ax);
    float t  = 1.0f - 2.0f * fast_rcp(e + 1.0f);   // e=inf -> t=1
    return copysignf(t, x);
}

__global__ __launch_bounds__(256) void mlp_kernel(
    const float* __restrict__ x,
    const float* __restrict__ Wd1, const float* __restrict__ bd1,
    const float* __restrict__ Wd2, const float* __restrict__ bd2,
    const float* __restrict__ Wu1, const float* __restrict__ bu1,
    const float* __restrict__ Wu2, const float* __restrict__ bu2,
    const float* __restrict__ Wm1, const float* __restrict__ bm1,
    const float* __restrict__ Wm2, const float* __restrict__ bm2,
    const float* __restrict__ v,
    float* __restrict__ out_mean, float* __restrict__ out_z,
    float* __restrict__ ws_a, float* __restrict__ ws_tp, float* __restrict__ ws_s)
{
    __shared__ float xs[ROWS][N];
    __shared__ float hd[ROWS][N];
    __shared__ float hu[ROWS][N];
    __shared__ float hm[ROWS][N];
    __shared__ float red1[4][3 * ROWS];
    __shared__ float red2[4][ROWS];

    const int tid = threadIdx.x;
    const int b0  = blockIdx.x * ROWS;

    // ---- load x rows (coalesced float4) ----
    {
        const float4* xg  = (const float4*)(x + (size_t)b0 * N);
        float4*       xsv = (float4*)&xs[0][0];
        #pragma unroll
        for (int i = 0; i < (ROWS * N / 4) / 256; ++i)
            xsv[tid + i * 256] = xg[tid + i * 256];
    }

    // prefetch v values (needed only in epilogue)
    float vv[ROWS];
    #pragma unroll
    for (int r = 0; r < ROWS; ++r)
        vv[r] = v[(size_t)(b0 + r) * N + tid];

    __syncthreads();

    // ---- layer 1 of all three MLPs (thread t = output neuron t) ----
    {
        float accd[ROWS], accu[ROWS], accm[ROWS];
        #pragma unroll
        for (int r = 0; r < ROWS; ++r) { accd[r] = 0.f; accu[r] = 0.f; accm[r] = 0.f; }
        const float4* wd = (const float4*)(Wd1 + (size_t)tid * N);
        const float4* wu = (const float4*)(Wu1 + (size_t)tid * N);
        const float4* wm = (const float4*)(Wm1 + (size_t)tid * N);
        #pragma unroll 4
        for (int k4 = 0; k4 < N / 4; ++k4) {
            float4 w1 = wd[k4];
            float4 w2 = wu[k4];
            float4 w3 = wm[k4];
            #pragma unroll
            for (int r = 0; r < ROWS; ++r) {
                float4 xv = ((const float4*)xs[r])[k4];
                accd[r] += w1.x * xv.x + w1.y * xv.y + w1.z * xv.z + w1.w * xv.w;
                accu[r] += w2.x * xv.x + w2.y * xv.y + w2.z * xv.z + w2.w * xv.w;
                accm[r] += w3.x * xv.x + w3.y * xv.y + w3.z * xv.z + w3.w * xv.w;
            }
        }
        float b1 = bd1[tid], b2 = bu1[tid], b3 = bm1[tid];
        #pragma unroll
        for (int r = 0; r < ROWS; ++r) {
            hd[r][tid] = sigmoidf(accd[r] + b1);
            hu[r][tid] = sigmoidf(accu[r] + b2);
            hm[r][tid] = fast_tanh(accm[r] + b3);
        }
    }
    __syncthreads();

    // ---- layer 2 of all three MLPs ----
    float d_[ROWS], u_[ROWS], m_[ROWS];
    {
        float accd[ROWS], accu[ROWS], accm[ROWS];
        #pragma unroll
        for (int r = 0; r < ROWS; ++r) { accd[r] = 0.f; accu[r] = 0.f; accm[r] = 0.f; }
        const float4* wd = (const float4*)(Wd2 + (size_t)tid * N);
        const float4* wu = (const float4*)(Wu2 + (size_t)tid * N);
        const float4* wm = (const float4*)(Wm2 + (size_t)tid * N);
        #pragma unroll 4
        for (int k4 = 0; k4 < N / 4; ++k4) {
            float4 w1 = wd[k4];
            float4 w2 = wu[k4];
            float4 w3 = wm[k4];
            #pragma unroll
            for (int r = 0; r < ROWS; ++r) {
                float4 hdv = ((const float4*)hd[r])[k4];
                float4 huv = ((const float4*)hu[r])[k4];
                float4 hmv = ((const float4*)hm[r])[k4];
                accd[r] += w1.x * hdv.x + w1.y * hdv.y + w1.z * hdv.z + w1.w * hdv.w;
                accu[r] += w2.x * huv.x + w2.y * huv.y + w2.z * huv.z + w2.w * huv.w;
                accm[r] += w3.x * hmv.x + w3.y * hmv.y + w3.z * hmv.z + w3.w * hmv.w;
            }
        }
        float b1 = bd2[tid], b2 = bu2[tid], b3 = bm2[tid];
        #pragma unroll
        for (int r = 0; r < ROWS; ++r) {
            d_[r] = sigmoidf(accd[r] + b1);
            u_[r] = sigmoidf(accu[r] + b2);
            m_[r] = fast_tanh(accm[r] + b3);
        }
    }

    // ---- epilogue: all reductions in 2 barrier rounds ----
    const int lane = tid & 63;
    const int wid  = tid >> 6;

    // round 1: per row {Su, q, Sv} -> 3*ROWS sums
    float inv_d[ROWS];
    float vals[3 * ROWS];
    #pragma unroll
    for (int r = 0; r < ROWS; ++r) {
        inv_d[r] = fast_rcp(d_[r]);
        vals[3 * r + 0] = u_[r];
        vals[3 * r + 1] = u_[r] * u_[r] * inv_d[r];
        vals[3 * r + 2] = vv[r];
    }
    #pragma unroll
    for (int k = 0; k < 3 * ROWS; ++k) {
        #pragma unroll
        for (int off = 32; off > 0; off >>= 1)
            vals[k] += __shfl_down(vals[k], off, 64);
    }
    if (lane == 0) {
        #pragma unroll
        for (int k = 0; k < 3 * ROWS; ++k) red1[wid][k] = vals[k];
    }
    __syncthreads();

    float a_[ROWS], s_[ROWS], tp_[ROWS], Sv_[ROWS];
    float vals2[ROWS];
    #pragma unroll
    for (int r = 0; r < ROWS; ++r) {
        float Su = red1[0][3*r+0] + red1[1][3*r+0] + red1[2][3*r+0] + red1[3][3*r+0];
        float q  = red1[0][3*r+1] + red1[1][3*r+1] + red1[2][3*r+1] + red1[3][3*r+1];
        Sv_[r]   = red1[0][3*r+2] + red1[1][3*r+2] + red1[2][3*r+2] + red1[3][3*r+2];
        float utDu  = q + EPS * Su * Su;
        float sqeta = rsqrtf(1.0f + utDu);
        float right = (1.0f - sqeta) / utDu;
        float a  = sqrtf(inv_d[r] + EPS);
        float s  = u_[r] * a + SQRT_EPS * (Su - u_[r]);
        float tp = right * (u_[r] * inv_d[r] + EPS * Su);
        a_[r] = a; s_[r] = s; tp_[r] = tp;
        vals2[r] = s * vv[r];
    }

    // round 2: per row {s.v}
    #pragma unroll
    for (int r = 0; r < ROWS; ++r) {
        #pragma unroll
        for (int off = 32; off > 0; off >>= 1)
            vals2[r] += __shfl_down(vals2[r], off, 64);
    }
    if (lane == 0) {
        #pragma unroll
        for (int r = 0; r < ROWS; ++r) red2[wid][r] = vals2[r];
    }
    __syncthreads();

    #pragma unroll
    for (int r = 0; r < ROWS; ++r) {
        const size_t row = (size_t)(b0 + r) * N + tid;
        float sv = red2[0][r] + red2[1][r] + red2[2][r] + red2[3][r];
        float z  = SQRT_EPS * Sv_[r] + (a_[r] - SQRT_EPS) * vv[r] - tp_[r] * sv + m_[r];
        out_mean[row] = m_[r];
        out_z[row]    = z;
        ws_a[row]     = a_[r];
        ws_tp[row]    = tp_[r];
        ws_s[row]     = s_[r];
    }
}

// R[b,i,j] = SQRT_EPS + (i==j)*(a_i - SQRT_EPS) - tp_i * s_j
__global__ __launch_bounds__(256) void r_kernel(
    const float* __restrict__ ws_a, const float* __restrict__ ws_tp,
    const float* __restrict__ ws_s, float* __restrict__ R)
{
    __shared__ float s_lds[N];
    __shared__ float a_lds[64];
    __shared__ float tp_lds[64];

    const int tid   = threadIdx.x;
    const int b     = blockIdx.x >> 2;
    const int chunk = blockIdx.x & 3;
    const int ibase = chunk * 64;

    s_lds[tid] = ws_s[(size_t)b * N + tid];
    if (tid < 64) {
        a_lds[tid]  = ws_a[(size_t)b * N + ibase + tid];
        tp_lds[tid] = ws_tp[(size_t)b * N + ibase + tid];
    }
    __syncthreads();

    const int j4 = tid & 63;      // which float4 along j
    const int il = tid >> 6;      // row within group of 4
    const nfloat4 sv = ((const nfloat4*)s_lds)[j4];
    nfloat4* Rb = (nfloat4*)(R + (size_t)b * N * N);
    const int jb = j4 * 4;

    #pragma unroll
    for (int it = 0; it < 16; ++it) {
        const int i_loc = it * 4 + il;
        const int i     = ibase + i_loc;
        const float a   = a_lds[i_loc];
        const float tp  = tp_lds[i_loc];
        nfloat4 o;
        o.x = SQRT_EPS - tp * sv.x;
        o.y = SQRT_EPS - tp * sv.y;
        o.z = SQRT_EPS - tp * sv.z;
        o.w = SQRT_EPS - tp * sv.w;
        if (i >= jb && i < jb + 4) {
            const float add = a - SQRT_EPS;
            if      (i == jb)     o.x += add;
            else if (i == jb + 1) o.y += add;
            else if (i == jb + 2) o.z += add;
            else                  o.w += add;
        }
        __builtin_nontemporal_store(o, &Rb[(size_t)i * 64 + j4]);
    }
}

extern "C" void kernel_launch(void* const* d_in, const int* in_sizes, int n_in,
                              void* d_out, int out_size, void* d_ws, size_t ws_size,
                              hipStream_t stream) {
    const float* x   = (const float*)d_in[0];
    const float* Wd1 = (const float*)d_in[1];
    const float* bd1 = (const float*)d_in[2];
    const float* Wd2 = (const float*)d_in[3];
    const float* bd2 = (const float*)d_in[4];
    const float* Wu1 = (const float*)d_in[5];
    const float* bu1 = (const float*)d_in[6];
    const float* Wu2 = (const float*)d_in[7];
    const float* bu2 = (const float*)d_in[8];
    const float* Wm1 = (const float*)d_in[9];
    const float* bm1 = (const float*)d_in[10];
    const float* Wm2 = (const float*)d_in[11];
    const float* bm2 = (const float*)d_in[12];
    const float* v   = (const float*)d_in[13];

    float* out      = (float*)d_out;
    float* out_mean = out;                                   // [1024,256]
    float* R        = out + (size_t)NB * N;                  // [1024,256,256]
    float* out_z    = R + (size_t)NB * N * N;                // [1024,256]

    float* wsf   = (float*)d_ws;
    float* ws_a  = wsf;                    // [1024,256]
    float* ws_tp = wsf + (size_t)NB * N;   // [1024,256]
    float* ws_s  = wsf + (size_t)2 * NB * N;

    mlp_kernel<<<NB / ROWS, 256, 0, stream>>>(
        x, Wd1, bd1, Wd2, bd2, Wu1, bu1, Wu2, bu2, Wm1, bm1, Wm2, bm2, v,
        out_mean, out_z, ws_a, ws_tp, ws_s);

    r_kernel<<<NB * 4, 256, 0, stream>>>(ws_a, ws_tp, ws_s, R);
}